// Round 2
// baseline (4214.427 us; speedup 1.0000x reference)
//
#include <hip/hip_runtime.h>

#define NB 262144
#define NT 64
#define NSTEP 63
#define DTF (1.0f/64.0f)
#define RRF 0.05f
#define INV_B (1.0/262144.0)
#define ACC_STRIDE 40

// ws layout (bytes)
#define ACC_BYTES   32768                       // 63*40 doubles = 20160 B, padded
#define STATE_OFF   ACC_BYTES
#define STATE_BYTES (NB*16)
#define H2_OFF      (STATE_OFF + STATE_BYTES)
#define H2_BYTES    (11*NB*4)
#define DWT_OFF     (H2_OFF + H2_BYTES)
#define DWT_BYTES   (63*NB*4)
#define ST_OFF      (DWT_OFF + DWT_BYTES)
#define ST_BYTES    (64*NB*4)
#define WS_NEED     ((size_t)ST_OFF + (size_t)ST_BYTES)

// ---------------- helpers ----------------
// Full-double reduction: per-thread values in double, double shuffles,
// double LDS partials, double atomics. Removes the fp32 cancellation in
// one-pass E[x^2]-m^2 that poisoned rsqrt(v+eps) when v ~ 1e-6*m^2.

template<int K>
__device__ __forceinline__ void block_reduce_atomic(const double* v, double* target) {
    __shared__ double red[4][K];
    const int tid  = threadIdx.x;
    const int lane = tid & 63;
    const int wave = tid >> 6;
    #pragma unroll
    for (int k = 0; k < K; ++k) {
        double x = v[k];
        #pragma unroll
        for (int off = 32; off > 0; off >>= 1) x += __shfl_xor(x, off, 64);
        if (lane == 0) red[wave][k] = x;
    }
    __syncthreads();
    if (tid < K) {
        double s = red[0][tid] + red[1][tid] + red[2][tid] + red[3][tid];
        atomicAdd(&target[tid], s);
    }
}

// ---------------- init: zero accumulators ----------------

__global__ void kinit(double* __restrict__ acc) {
    int i = blockIdx.x * 256 + threadIdx.x;
    if (i < NSTEP * ACC_STRIDE) acc[i] = 0.0;
}

// ---------------- transpose (B,64) -> (64,B), optionally time-diff ----------------

__global__ __launch_bounds__(256) void ktrans(const float* __restrict__ in,
                                              float* __restrict__ out, int diffmode) {
    __shared__ float tile[64][65];
    const int b0 = blockIdx.x * 64;
    const int tx = threadIdx.x & 63;
    const int ty = threadIdx.x >> 6;
    #pragma unroll
    for (int i = 0; i < 16; ++i) {
        int p = ty * 16 + i;
        tile[p][tx] = in[(size_t)(b0 + p) * NT + tx];
    }
    __syncthreads();
    if (diffmode) {
        #pragma unroll
        for (int i = 0; i < 16; ++i) {
            int tt = ty * 16 + i;
            if (tt < 63) out[(size_t)tt * NB + b0 + tx] = tile[tx][tt + 1] - tile[tx][tt];
        }
    } else {
        #pragma unroll
        for (int i = 0; i < 16; ++i) {
            int tt = ty * 16 + i;
            out[(size_t)tt * NB + b0 + tx] = tile[tx][tt];
        }
    }
}

// ---------------- phase A: state update + cov(z) reduction ----------------

template<bool TR>
__global__ __launch_bounds__(256) void kA(
    const float* __restrict__ Wraw, const float* __restrict__ Sraw,
    const float* __restrict__ dWt,  const float* __restrict__ St,
    float4* __restrict__ state, double* __restrict__ acc, int t,
    const float* __restrict__ g3, const float* __restrict__ b3,
    const float* __restrict__ y0i, const float* __restrict__ y1i,
    const float* __restrict__ z0i, const float* __restrict__ z1i)
{
    const int b = blockIdx.x * 256 + threadIdx.x;
    float dw, s;
    if (TR) {
        dw = dWt[(size_t)t * NB + b];
        s  = St [(size_t)t * NB + b];
    } else {
        const float* wr = Wraw + (size_t)b * NT + t;
        dw = wr[1] - wr[0];
        s  = Sraw[(size_t)b * NT + t];
    }
    float z0, z1, x0, x1, y0, y1;
    if (t == 0) {
        z0 = z0i[0]; z1 = z1i[0];
        x0 = 1.f; x1 = 0.f; y0 = y0i[0]; y1 = y1i[0];
    } else {
        const double* a = acc + (size_t)(t - 1) * ACC_STRIDE;
        double m3 = a[36] * INV_B;
        double v3 = a[37] * INV_B - m3 * m3; v3 = v3 < 0.0 ? 0.0 : v3;
        double r3 = 1.0 / sqrt(v3 + 1e-6);
        double g  = (double)g3[t - 1], bb = (double)b3[t - 1];
        z0 = (float)(g * (a[38] - m3) * r3 + bb);
        z1 = (float)(g * (a[39] - m3) * r3 + bb);
        float4 s4 = state[b];
        x0 = s4.x; x1 = s4.y; y0 = s4.z; y1 = s4.w;
    }
    float x0n = x0 + (0.05f*s*x0 + 0.01f*s*x1)*DTF + (0.2f*s*x0 + 0.1f*s*x1)*dw;
    float y0n = y0 + RRF*y0*DTF + z0*dw;
    float y1n = y1 + RRF*y1*DTF + z1*dw;
    float x1n = x1 - y1n*DTF;
    state[b] = make_float4(x0n, x1n, y0n, y1n);
    double d0 = (double)x0n, d1 = (double)x1n, d2 = (double)y0n, d3 = (double)y1n;
    double v[14] = { d0, d1, d2, d3,
                     d0*d0, d0*d1, d0*d2, d0*d3,
                     d1*d1, d1*d2, d1*d3,
                     d2*d2, d2*d3, d3*d3 };
    block_reduce_atomic<14>(v, acc + (size_t)t * ACC_STRIDE);
}

// ---------------- phase B: layers 0-2, write h2_pre, reduce its stats ----------------

__global__ __launch_bounds__(256) void kB(
    const float4* __restrict__ state, float* __restrict__ h2pre,
    double* __restrict__ acc, int t,
    const float* __restrict__ g0, const float* __restrict__ b0,
    const float* __restrict__ W0,
    const float* __restrict__ g1, const float* __restrict__ b1,
    const float* __restrict__ W1)
{
    const int b = blockIdx.x * 256 + threadIdx.x;
    float4 s4 = state[b];  // issue early

    const double* a = acc + (size_t)t * ACC_STRIDE;
    double m[4];
    #pragma unroll
    for (int i = 0; i < 4; ++i) m[i] = a[i] * INV_B;
    double C[4][4];
    {
        int p = 4;
        #pragma unroll
        for (int i = 0; i < 4; ++i)
            #pragma unroll
            for (int k = i; k < 4; ++k) {
                double c = a[p++] * INV_B - m[i] * m[k];
                C[i][k] = c; C[k][i] = c;
            }
    }
    const float* w0 = W0 + (size_t)t * 44;
    float w0f[4][11];
    #pragma unroll
    for (int i = 0; i < 4; ++i)
        #pragma unroll
        for (int j = 0; j < 11; ++j) w0f[i][j] = w0[i * 11 + j];

    double u[4]; float uf[4], mf[4], b0f[4];
    #pragma unroll
    for (int i = 0; i < 4; ++i) {
        double vi = C[i][i]; vi = vi < 0.0 ? 0.0 : vi;
        double ri = 1.0 / sqrt(vi + 1e-6);
        u[i]  = (double)g0[(size_t)t * 4 + i] * ri;
        uf[i] = (float)u[i];
        mf[i] = (float)m[i];
        b0f[i] = b0[(size_t)t * 4 + i];
    }
    double M[4][4];
    #pragma unroll
    for (int i = 0; i < 4; ++i)
        #pragma unroll
        for (int k = 0; k < 4; ++k) M[i][k] = u[i] * u[k] * C[i][k];

    float mean1[11], q1[11], b1f[11];
    #pragma unroll
    for (int j = 0; j < 11; ++j) {
        double mj = 0.0, vj = 0.0;
        #pragma unroll
        for (int i = 0; i < 4; ++i) {
            mj += (double)b0f[i] * (double)w0f[i][j];
            double ti = 0.0;
            #pragma unroll
            for (int k = 0; k < 4; ++k) ti += M[i][k] * (double)w0f[k][j];
            vj += (double)w0f[i][j] * ti;
        }
        vj = vj < 0.0 ? 0.0 : vj;
        double rj = 1.0 / sqrt(vj + 1e-6);
        mean1[j] = (float)mj;
        q1[j]    = (float)((double)g1[(size_t)t * 11 + j] * rj);
        b1f[j]   = b1[(size_t)t * 11 + j];
    }

    float h0[4] = { uf[0]*(s4.x - mf[0]) + b0f[0],
                    uf[1]*(s4.y - mf[1]) + b0f[1],
                    uf[2]*(s4.z - mf[2]) + b0f[2],
                    uf[3]*(s4.w - mf[3]) + b0f[3] };
    float h1[11];
    #pragma unroll
    for (int j = 0; j < 11; ++j) {
        float hp = h0[0]*w0f[0][j] + h0[1]*w0f[1][j] + h0[2]*w0f[2][j] + h0[3]*w0f[3][j];
        h1[j] = fmaxf(q1[j] * (hp - mean1[j]) + b1f[j], 0.f);
    }
    const float* w1 = W1 + (size_t)t * 121;
    double v[22];
    #pragma unroll
    for (int j = 0; j < 11; ++j) {
        float hp = 0.f;
        #pragma unroll
        for (int i = 0; i < 11; ++i) hp += h1[i] * w1[i * 11 + j];
        h2pre[(size_t)j * NB + b] = hp;
        double hd = (double)hp;
        v[j] = hd; v[11 + j] = hd * hd;
    }
    block_reduce_atomic<22>(v, acc + (size_t)t * ACC_STRIDE + 14);
}

// ---------------- phase C: layer 3, reduce h3 stats + store rows 0/1 ----------------

__global__ __launch_bounds__(256) void kC(
    const float* __restrict__ h2pre, double* __restrict__ acc, int t,
    const float* __restrict__ g2, const float* __restrict__ b2,
    const float* __restrict__ W2, const float* __restrict__ bias2)
{
    const int b = blockIdx.x * 256 + threadIdx.x;
    const double* a = acc + (size_t)t * ACC_STRIDE;
    float m2f[11], q2[11], b2f[11], w2f[11];
    #pragma unroll
    for (int j = 0; j < 11; ++j) {
        double mj = a[14 + j] * INV_B;
        double vj = a[25 + j] * INV_B - mj * mj; vj = vj < 0.0 ? 0.0 : vj;
        double rj = 1.0 / sqrt(vj + 1e-6);
        m2f[j] = (float)mj;
        q2[j]  = (float)((double)g2[(size_t)t * 11 + j] * rj);
        b2f[j] = b2[(size_t)t * 11 + j];
        w2f[j] = W2[(size_t)t * 11 + j];
    }
    float h3 = bias2[t];
    #pragma unroll
    for (int j = 0; j < 11; ++j) {
        float hv = h2pre[(size_t)j * NB + b];
        float h2 = fmaxf(q2[j] * (hv - m2f[j]) + b2f[j], 0.f);
        h3 += h2 * w2f[j];
    }
    double* aw = acc + (size_t)t * ACC_STRIDE;
    if (b == 0) aw[38] = (double)h3;
    if (b == 1) aw[39] = (double)h3;
    double hd = (double)h3;
    double v[2] = { hd, hd * hd };
    block_reduce_atomic<2>(v, aw + 36);
}

// ---------------- final update + output ----------------

template<bool TR>
__global__ __launch_bounds__(256) void kF(
    const float* __restrict__ Wraw, const float* __restrict__ Sraw,
    const float* __restrict__ dWt,  const float* __restrict__ St,
    const float4* __restrict__ state, float* __restrict__ out,
    const double* __restrict__ acc,
    const float* __restrict__ g3, const float* __restrict__ b3)
{
    const int b = blockIdx.x * 256 + threadIdx.x;
    const double* a = acc + (size_t)62 * ACC_STRIDE;
    double m3 = a[36] * INV_B;
    double v3 = a[37] * INV_B - m3 * m3; v3 = v3 < 0.0 ? 0.0 : v3;
    double r3 = 1.0 / sqrt(v3 + 1e-6);
    double g  = (double)g3[62], bb = (double)b3[62];
    float z0 = (float)(g * (a[38] - m3) * r3 + bb);
    float z1 = (float)(g * (a[39] - m3) * r3 + bb);

    float dw, s;
    if (TR) {
        dw = dWt[(size_t)62 * NB + b];
        s  = St [(size_t)63 * NB + b];
    } else {
        const float* wr = Wraw + (size_t)b * NT + 62;
        dw = wr[1] - wr[0];
        s  = Sraw[(size_t)b * NT + 63];
    }
    float4 s4 = state[b];
    float x0 = s4.x, x1 = s4.y, y0 = s4.z, y1 = s4.w;
    float x0n = x0 + (0.05f*s*x0 + 0.01f*s*x1)*DTF + (0.2f*s*x0 + 0.1f*s*x1)*dw;
    float y0n = y0 + RRF*y0*DTF + z0*dw;
    float y1n = y1 + RRF*y1*DTF + z1*(-dw);
    float x1n = x1 - y1n*DTF;
    out[b]          = x0n;
    out[NB + b]     = x1n;
    out[2*NB + b]   = y0n;
    out[3*NB + b]   = y1n;
}

// ---------------- launcher ----------------

extern "C" void kernel_launch(void* const* d_in, const int* in_sizes, int n_in,
                              void* d_out, int out_size, void* d_ws, size_t ws_size,
                              hipStream_t stream)
{
    (void)in_sizes; (void)n_in; (void)out_size;
    const float* W   = (const float*)d_in[0];
    const float* S   = (const float*)d_in[1];
    const float* y0i = (const float*)d_in[2];
    const float* y1i = (const float*)d_in[3];
    const float* z0i = (const float*)d_in[4];
    const float* z1i = (const float*)d_in[5];
    const float* g0  = (const float*)d_in[6];
    const float* b0  = (const float*)d_in[7];
    const float* W0  = (const float*)d_in[8];
    const float* g1  = (const float*)d_in[9];
    const float* b1  = (const float*)d_in[10];
    const float* W1  = (const float*)d_in[11];
    const float* g2  = (const float*)d_in[12];
    const float* b2  = (const float*)d_in[13];
    const float* W2  = (const float*)d_in[14];
    const float* bias2 = (const float*)d_in[15];
    const float* g3  = (const float*)d_in[16];
    const float* b3  = (const float*)d_in[17];
    float* out = (float*)d_out;

    char* ws = (char*)d_ws;
    double* acc   = (double*)ws;
    float4* state = (float4*)(ws + STATE_OFF);
    float* h2pre  = (float*)(ws + H2_OFF);
    float* dWt    = (float*)(ws + DWT_OFF);
    float* St     = (float*)(ws + ST_OFF);
    const bool tr = ws_size >= WS_NEED;

    kinit<<<10, 256, 0, stream>>>(acc);
    if (tr) {
        ktrans<<<NB/64, 256, 0, stream>>>(W, dWt, 1);
        ktrans<<<NB/64, 256, 0, stream>>>(S, St, 0);
    }
    dim3 grid(NB/256), blk(256);
    for (int t = 0; t < NSTEP; ++t) {
        if (tr) kA<true ><<<grid, blk, 0, stream>>>(W, S, dWt, St, state, acc, t, g3, b3, y0i, y1i, z0i, z1i);
        else    kA<false><<<grid, blk, 0, stream>>>(W, S, dWt, St, state, acc, t, g3, b3, y0i, y1i, z0i, z1i);
        kB<<<grid, blk, 0, stream>>>(state, h2pre, acc, t, g0, b0, W0, g1, b1, W1);
        kC<<<grid, blk, 0, stream>>>(h2pre, acc, t, g2, b2, W2, bias2);
    }
    if (tr) kF<true ><<<grid, blk, 0, stream>>>(W, S, dWt, St, state, out, acc, g3, b3);
    else    kF<false><<<grid, blk, 0, stream>>>(W, S, dWt, St, state, out, acc, g3, b3);
}